// Round 8
// baseline (978.332 us; speedup 1.0000x reference)
//
#include <hip/hip_runtime.h>

#define NN     50000
#define E_RAW  800000
#define ETOT   (E_RAW + NN)   /* 850000: edges + self loops */
#define FIN    128
#define FH     256            /* HEADS*HID */
#define NEG    0.2f
#define BCAP   64             /* bucket capacity; P(deg>64) ~ 1e-18 */

/* Counting-sort CSR build.  R9: global atomics cap ~11 ops/ns -> LDS
   histograms.  R14: scatter needs its own 1024-thr dispatch.  R19: agg1
   codegen is fragile -- touch nothing in its body.  R21: cooperative
   LAUNCH API kills the harness; R23 replaces it with a manual resident-grid
   barrier (atomic + spin + fences = what grid.sync() is made of).
   R22: scan-byte halving proved count/scat are NOT BW-bound; the invariant
   ~136 us non-agg1 budget is small kernels + dispatch overhead. */
#define P_PART 4
#define DPW    12500            /* dsts per partition, 50KB LDS */
#define R_REP  64
#define EPW    (E_RAW / R_REP)  /* 12500 edges per replica */
#define CNT_WGS (P_PART * R_REP) /* 256 */
#define PREP_WGS 8              /* W1 transpose: 8 x 4096 elems */
#define OFF_NB  ((NN + 255) / 256)   /* 196 offset blocks */
#define GEMM_NB ((NN + 63) / 64)     /* 782 gemm blocks */
#define AGG_GRID 2048           /* 8 blocks/CU x 256 CU: exactly resident */

typedef __attribute__((ext_vector_type(8))) short s16x8;
typedef __attribute__((ext_vector_type(4))) float f32x4;

static __device__ __forceinline__ float leaky(float v) { return v > 0.f ? v : NEG * v; }

// RNE float->bf16
static __device__ __forceinline__ unsigned short f2bf(float f) {
    unsigned u = __float_as_uint(f);
    unsigned r = u + 0x7fffu + ((u >> 16) & 1u);
    return (unsigned short)(r >> 16);
}

// ---------------------------------------------------------------------------
// D1: count pass + W1 prep.
// ---------------------------------------------------------------------------
__global__ __launch_bounds__(1024) void k_count(const int* __restrict__ ei,
                                                const float* __restrict__ W1,
                                                unsigned short* __restrict__ Wt_bf,
                                                unsigned short* __restrict__ pcnt16)
{
    const int t = threadIdx.x;
    if (blockIdx.x >= CNT_WGS) {
        const int base = (blockIdx.x - CNT_WGS) * 4096;
        for (int i = t; i < 4096; i += 1024) {
            int idx = base + i;                 // < 32768
            int k = idx >> 8, col = idx & 255;
            Wt_bf[col * FIN + k] = f2bf(W1[k * FH + col]);
        }
        return;
    }
    __shared__ int lcnt[DPW];
    const int p  = blockIdx.x >> 6;
    const int r  = blockIdx.x & 63;
    const int lo = p * DPW;
    for (int i = t; i < DPW; i += 1024) lcnt[i] = 0;
    __syncthreads();
    const int ebase = r * EPW, eend = ebase + EPW;
    for (int e0 = ebase + t * 4; e0 < eend; e0 += 4096) {
        int4 dv4 = *(const int4*)&ei[E_RAW + e0];   // coalesced 16B
#pragma unroll
        for (int k = 0; k < 4; k++) {
            unsigned rel = (unsigned)((&dv4.x)[k] - lo);
            if (rel < DPW) atomicAdd(&lcnt[rel], 1);   // LDS, no return
        }
    }
    __syncthreads();
    for (int i = t; i < DPW; i += 1024)
        pcnt16[r * NN + lo + i] = (unsigned short)lcnt[i];
}

// ---------------------------------------------------------------------------
// D2: FUSED offsets + gemm.
// ---------------------------------------------------------------------------
__global__ __launch_bounds__(256) void k_gx(const float* __restrict__ x,
                                            const unsigned short* __restrict__ Wt_bf,
                                            const float* __restrict__ att_src,
                                            const float* __restrict__ att_dst,
                                            const unsigned short* __restrict__ pcnt16,
                                            unsigned short* __restrict__ soff16,
                                            int* __restrict__ cnt,
                                            unsigned short* __restrict__ csr16,
                                            unsigned short* __restrict__ h1b,
                                            float* __restrict__ a_s,
                                            float* __restrict__ a_d)
{
    const int t = threadIdx.x;
    if (blockIdx.x < OFF_NB) {
        int d = blockIdx.x * 256 + t;
        if (d >= NN) return;
        int run = 1;                     // slot 0 = self loop
#pragma unroll
        for (int r = 0; r < R_REP; r++) {
            soff16[r * NN + d] = (unsigned short)run;
            run += pcnt16[r * NN + d];
        }
        cnt[d] = run;                    // clamped at use
        csr16[(size_t)d << 6] = (unsigned short)d;   // self-loop src
        return;
    }

    // ---------------- gemm path ----------------
    __shared__ unsigned short Sbuf[64 * 256];
    const int w    = t >> 6;
    const int lane = t & 63;
    const int li   = lane & 15;
    const int q8   = (lane >> 4) * 8;
    const int quad = lane >> 4;
    const int n0   = (blockIdx.x - OFF_NB) * 64;

    {
        const int node_l = t >> 2;
        const int k0 = (t & 3) * 32;
        int nn = n0 + node_l; if (nn >= NN) nn = NN - 1;
        const float* xp = &x[(size_t)nn * FIN + k0];
        unsigned short* xd = &Sbuf[node_l * 136 + k0];
#pragma unroll
        for (int i = 0; i < 8; i++) {
            float4 v = *(const float4*)&xp[i * 4];
            xd[i * 4 + 0] = f2bf(v.x);
            xd[i * 4 + 1] = f2bf(v.y);
            xd[i * 4 + 2] = f2bf(v.z);
            xd[i * 4 + 3] = f2bf(v.w);
        }
    }
    __syncthreads();

    f32x4 acc[4][4];
#pragma unroll
    for (int i = 0; i < 4; i++)
#pragma unroll
        for (int j = 0; j < 4; j++) acc[i][j] = (f32x4){0.f, 0.f, 0.f, 0.f};

#pragma unroll
    for (int kki = 0; kki < 4; kki++) {
        const int kk = kki * 32;
        s16x8 af[4], bf[4];
#pragma unroll
        for (int n16 = 0; n16 < 4; n16++) {
            int col = w * 64 + n16 * 16 + li;
            bf[n16] = *(const s16x8*)&Wt_bf[col * FIN + kk + q8];
        }
#pragma unroll
        for (int m16 = 0; m16 < 4; m16++)
            af[m16] = *(const s16x8*)&Sbuf[(m16 * 16 + li) * 136 + kk + q8];
#pragma unroll
        for (int m16 = 0; m16 < 4; m16++)
#pragma unroll
            for (int n16 = 0; n16 < 4; n16++)
                acc[m16][n16] = __builtin_amdgcn_mfma_f32_16x16x32_bf16(
                    af[m16], bf[n16], acc[m16][n16], 0, 0, 0);
    }

    // epilogue A: per-head attention logits
    {
        float as_c[4], ad_c[4];
#pragma unroll
        for (int n16 = 0; n16 < 4; n16++) {
            int col = w * 64 + n16 * 16 + li;
            as_c[n16] = att_src[col];
            ad_c[n16] = att_dst[col];
        }
#pragma unroll
        for (int m16 = 0; m16 < 4; m16++) {
            float ps[4], pd[4];
#pragma unroll
            for (int reg = 0; reg < 4; reg++) {
                float s = 0.f, d = 0.f;
#pragma unroll
                for (int n16 = 0; n16 < 4; n16++) {
                    s += acc[m16][n16][reg] * as_c[n16];
                    d += acc[m16][n16][reg] * ad_c[n16];
                }
                ps[reg] = s; pd[reg] = d;
            }
#pragma unroll
            for (int off = 1; off < 16; off <<= 1) {
#pragma unroll
                for (int reg = 0; reg < 4; reg++) {
                    ps[reg] += __shfl_xor(ps[reg], off);
                    pd[reg] += __shfl_xor(pd[reg], off);
                }
            }
            if (li == 0) {
#pragma unroll
                for (int reg = 0; reg < 4; reg++) {
                    int node = n0 + m16 * 16 + quad * 4 + reg;
                    if (node < NN) {
                        a_s[node * 4 + w] = ps[reg];
                        a_d[node * 4 + w] = pd[reg];
                    }
                }
            }
        }
    }

    // epilogue B: bf16 store via LDS round-trip
    __syncthreads();
#pragma unroll
    for (int m16 = 0; m16 < 4; m16++)
#pragma unroll
        for (int n16 = 0; n16 < 4; n16++)
#pragma unroll
            for (int reg = 0; reg < 4; reg++)
                Sbuf[(m16 * 16 + quad * 4 + reg) * FH + w * 64 + n16 * 16 + li] =
                    f2bf(acc[m16][n16][reg]);
    __syncthreads();
    {
        const int node_l = t >> 2;
        const int c0 = (t & 3) * 64;
        int node = n0 + node_l;
        if (node < NN) {
#pragma unroll
            for (int i = 0; i < 8; i++)
                *(uint4*)&h1b[(size_t)node * FH + c0 + i * 8] =
                    *(const uint4*)&Sbuf[node_l * FH + c0 + i * 8];
        }
    }
}

// ---------------------------------------------------------------------------
// D3: scatter into contiguous buckets (u16 payload).  Also zeroes the grid
// barrier word for D4 (stream order publishes it; each graph replay
// re-zeroes).  1024-thread WGs (R14 lesson: do NOT shrink).
// ---------------------------------------------------------------------------
__global__ __launch_bounds__(1024) void k_scat2(const int* __restrict__ ei,
                                                const unsigned short* __restrict__ soff16,
                                                unsigned short* __restrict__ csr16,
                                                int* __restrict__ bar)
{
    if (blockIdx.x == 0 && threadIdx.x == 0) *bar = 0;
    __shared__ int cur[DPW];
    const int t  = threadIdx.x;
    const int p  = blockIdx.x >> 6;
    const int r  = blockIdx.x & 63;
    const int lo = p * DPW;
    for (int i = t; i < DPW; i += 1024)
        cur[i] = soff16[r * NN + lo + i];
    __syncthreads();
    const int ebase = r * EPW, eend = ebase + EPW;
    for (int e0 = ebase + t * 4; e0 < eend; e0 += 4096) {
        int4 sv4 = *(const int4*)&ei[e0];           // coalesced 16B (src)
        int4 dv4 = *(const int4*)&ei[E_RAW + e0];   // coalesced 16B (dst)
#pragma unroll
        for (int k = 0; k < 4; k++) {
            int d = (&dv4.x)[k];
            unsigned rel = (unsigned)(d - lo);
            if (rel < DPW) {
                int pos = atomicAdd(&cur[rel], 1);  // LDS ds_add_rtn
                if (pos < BCAP)
                    csr16[((size_t)d << 6) + pos] = (unsigned short)(&sv4.x)[k];
            }
        }
    }
}

// ---------------------------------------------------------------------------
// D4: FUSED agg1 + agg2 with a manual resident-grid barrier.
// 2048 blocks x 256 thr, LB(256,8): compiler caps VGPR<=64 (body needs 24),
// LDS 0 -> 8 blocks/CU x 256 CU = all 2048 co-resident by construction, so
// the atomic+spin barrier cannot starve (this is grid.sync()'s own
// implementation, minus the launch API that kills the harness).  Spin has a
// ~17ms timeout escape: a residency surprise yields a visibly-wrong answer,
// not a hang.  Phase 1 = EXACT R20 agg1 body grid-strided (12500*4 == NN:
// no early returns before the barrier).  Phase 2 = EXACT agg2 grid-strided.
// ---------------------------------------------------------------------------
__global__ __launch_bounds__(256, 8) void k_agg(const int* __restrict__ cnt,
                                                const unsigned short* __restrict__ csr16,
                                                const float* __restrict__ a_s1,
                                                const float* __restrict__ a_d1,
                                                const unsigned short* __restrict__ h1b,
                                                const float* __restrict__ b1,
                                                const float* __restrict__ W2,
                                                const float* __restrict__ att_src2,
                                                const float* __restrict__ att_dst2,
                                                float4* __restrict__ nd4,
                                                const float* __restrict__ b2,
                                                float* __restrict__ out,
                                                int* __restrict__ bar)
{
    const int t = threadIdx.x;

    // ---- phase 1: layer-1 aggregation (v1 body, grid-stride) ----
    for (int wk = blockIdx.x; wk < NN / 4; wk += AGG_GRID) {
        const int lane = t & 63;
        const int n = wk * 4 + (t >> 6);         // < NN always (12500*4==NN)
        int m = cnt[n]; if (m > BCAP) m = BCAP;
        const int h = lane >> 4;
        const float ad_h = a_d1[n * 4 + h];
        float acc0 = 0.f, acc1 = 0.f, acc2 = 0.f, acc3 = 0.f, z = 0.f;
        const unsigned short* sp = &csr16[(size_t)n << 6];
#pragma unroll 4
        for (int j = 0; j < m; j++) {
            int s = sp[j];                       // wave-uniform 2B
            float as_h = a_s1[s * 4 + h];
            float ex = __expf(leaky(as_h + ad_h));
            unsigned long long wv =
                *(const unsigned long long*)(h1b + (size_t)s * FH + lane * 4);
            unsigned lo = (unsigned)wv, hi = (unsigned)(wv >> 32);
            acc0 += __uint_as_float(lo << 16) * ex;
            acc1 += __uint_as_float(lo & 0xffff0000u) * ex;
            acc2 += __uint_as_float(hi << 16) * ex;
            acc3 += __uint_as_float(hi & 0xffff0000u) * ex;
            z += ex;
        }
        const int c0 = lane * 4;
        float4 bb = *(const float4*)&b1[c0];
        float v0 = acc0 / z + bb.x;
        float v1 = acc1 / z + bb.y;
        float v2 = acc2 / z + bb.z;
        float v3 = acc3 / z + bb.w;
        v0 = v0 > 0.f ? v0 : __expf(v0) - 1.f;   // ELU
        v1 = v1 > 0.f ? v1 : __expf(v1) - 1.f;
        v2 = v2 > 0.f ? v2 : __expf(v2) - 1.f;
        v3 = v3 > 0.f ? v3 : __expf(v3) - 1.f;
        float4 w2a = *(const float4*)&W2[c0 * 2];
        float4 w2b = *(const float4*)&W2[c0 * 2 + 4];
        float s0 = v0 * w2a.x + v1 * w2a.z + v2 * w2b.x + v3 * w2b.z;
        float s1 = v0 * w2a.y + v1 * w2a.w + v2 * w2b.y + v3 * w2b.w;
#pragma unroll
        for (int off = 32; off; off >>= 1) {
            s0 += __shfl_xor(s0, off);
            s1 += __shfl_xor(s1, off);
        }
        if (lane == 0) {
            float4 nd;
            nd.x = s0; nd.y = s1;
            nd.z = s0 * att_src2[0] + s1 * att_src2[1];
            nd.w = s0 * att_dst2[0] + s1 * att_dst2[1];
            nd4[n] = nd;
        }
    }

    // ---- resident-grid barrier (release/acquire) ----
    __threadfence();
    __syncthreads();
    if (t == 0) {
        atomicAdd(bar, 1);
        long long t0 = clock64();
        while (__hip_atomic_load(bar, __ATOMIC_ACQUIRE,
                                 __HIP_MEMORY_SCOPE_AGENT) < AGG_GRID) {
            __builtin_amdgcn_s_sleep(4);
            if (clock64() - t0 > (42LL << 20)) break;   // ~17ms anti-hang
        }
    }
    __syncthreads();
    __threadfence();

    // ---- phase 2: layer-2 aggregation (16 lanes per dst, grid-stride) ----
    for (int u = blockIdx.x; u < NN / 16; u += AGG_GRID) {
        const int l = t & 15;
        const int n = u * 16 + (t >> 4);         // < NN always (3125*16==NN)
        int m = cnt[n]; if (m > BCAP) m = BCAP;
        const unsigned short* sp = &csr16[(size_t)n << 6];
        const float ad = nd4[n].w;
        float z = 0.f, a0 = 0.f, a1 = 0.f;
        for (int j = l; j < m; j += 16) {
            int s = sp[j];
            float4 f = nd4[s];
            float ex = __expf(leaky(f.z + ad));
            z  += ex;
            a0 += f.x * ex;
            a1 += f.y * ex;
        }
#pragma unroll
        for (int off = 8; off; off >>= 1) {
            z  += __shfl_xor(z, off);
            a0 += __shfl_xor(a0, off);
            a1 += __shfl_xor(a1, off);
        }
        if (l == 0) {
            out[n * 2 + 0] = a0 / z + b2[0];
            out[n * 2 + 1] = a1 / z + b2[1];
        }
    }
}

extern "C" void kernel_launch(void* const* d_in, const int* in_sizes, int n_in,
                              void* d_out, int out_size, void* d_ws, size_t ws_size,
                              hipStream_t stream)
{
    const float* x        = (const float*)d_in[0];
    const int*   ei       = (const int*)d_in[1];
    const float* W1       = (const float*)d_in[2];
    const float* att_src1 = (const float*)d_in[3];
    const float* att_dst1 = (const float*)d_in[4];
    const float* b1       = (const float*)d_in[5];
    const float* W2       = (const float*)d_in[6];
    const float* att_src2 = (const float*)d_in[7];
    const float* att_dst2 = (const float*)d_in[8];
    const float* b2       = (const float*)d_in[9];
    float* out = (float*)d_out;

    // --- workspace layout (all regions 16B aligned) ---
    unsigned short* csr16 = (unsigned short*)d_ws;           // NN*64*2 = 6.4 MB
    unsigned short* h1b   = csr16 + (size_t)NN * 64;         // 25.6 MB
    unsigned short* Wt_bf = h1b + (size_t)NN * FH;           // 64 KB
    unsigned short* pcnt16 = Wt_bf + FH * FIN;               // NN*64*2 = 6.4 MB
    unsigned short* soff16 = pcnt16 + (size_t)NN * R_REP;    // 6.4 MB
    int*    cnt   = (int*)(soff16 + (size_t)NN * R_REP);     // 200 KB
    float*  a_s1  = (float*)(cnt + NN);                      // 800 KB
    float*  a_d1  = a_s1 + (size_t)NN * 4;                   // 800 KB
    float4* nd4   = (float4*)(a_d1 + (size_t)NN * 4);        // 800 KB
    int*    bar   = (int*)(nd4 + NN);                        // 16 B

    k_count<<<CNT_WGS + PREP_WGS, 1024, 0, stream>>>(ei, W1, Wt_bf, pcnt16);
    k_gx<<<OFF_NB + GEMM_NB, 256, 0, stream>>>(x, Wt_bf, att_src1, att_dst1,
                                               pcnt16, soff16, cnt, csr16,
                                               h1b, a_s1, a_d1);
    k_scat2<<<CNT_WGS, 1024, 0, stream>>>(ei, soff16, csr16, bar);
    k_agg<<<AGG_GRID, 256, 0, stream>>>(cnt, csr16, a_s1, a_d1, h1b,
                                        b1, W2, att_src2, att_dst2, nd4,
                                        b2, out, bar);
}

// Round 9
// 737.651 us; speedup vs baseline: 1.3263x; 1.3263x over previous
//
#include <hip/hip_runtime.h>

#define NN     50000
#define E_RAW  800000
#define ETOT   (E_RAW + NN)   /* 850000: edges + self loops */
#define FIN    128
#define FH     256            /* HEADS*HID */
#define NEG    0.2f
#define BCAP   64             /* bucket capacity; P(deg>64) ~ 1e-18 */

/* Counting-sort CSR build.  R9: global atomics cap ~11 ops/ns -> LDS
   histograms.  R14: scatter needs its own 1024-thr dispatch.  R19: agg1
   codegen is fragile -- touch nothing in its body.  R21: cooperative
   LAUNCH API kills the harness.  R23: manual resident-grid barrier is
   CORRECT but s_sleep(4)+ACQUIRE polls = ~8 device-scope polls/cycle on one
   line + per-poll L1 invalidation -> 900us spin storm.  R24 fix:
   s_sleep(127) (32x fewer polls) + RELAXED polls (no L1 inv; the
   syncthreads+threadfence after the loop is the acquire). */
#define P_PART 4
#define DPW    12500            /* dsts per partition, 50KB LDS */
#define R_REP  64
#define EPW    (E_RAW / R_REP)  /* 12500 edges per replica */
#define CNT_WGS (P_PART * R_REP) /* 256 */
#define PREP_WGS 8              /* W1 transpose: 8 x 4096 elems */
#define OFF_NB  ((NN + 255) / 256)   /* 196 offset blocks */
#define GEMM_NB ((NN + 63) / 64)     /* 782 gemm blocks */
#define AGG_GRID 2048           /* 8 blocks/CU x 256 CU: exactly resident */

typedef __attribute__((ext_vector_type(8))) short s16x8;
typedef __attribute__((ext_vector_type(4))) float f32x4;

static __device__ __forceinline__ float leaky(float v) { return v > 0.f ? v : NEG * v; }

// RNE float->bf16
static __device__ __forceinline__ unsigned short f2bf(float f) {
    unsigned u = __float_as_uint(f);
    unsigned r = u + 0x7fffu + ((u >> 16) & 1u);
    return (unsigned short)(r >> 16);
}

// ---------------------------------------------------------------------------
// D1: count pass + W1 prep.
// ---------------------------------------------------------------------------
__global__ __launch_bounds__(1024) void k_count(const int* __restrict__ ei,
                                                const float* __restrict__ W1,
                                                unsigned short* __restrict__ Wt_bf,
                                                unsigned short* __restrict__ pcnt16)
{
    const int t = threadIdx.x;
    if (blockIdx.x >= CNT_WGS) {
        const int base = (blockIdx.x - CNT_WGS) * 4096;
        for (int i = t; i < 4096; i += 1024) {
            int idx = base + i;                 // < 32768
            int k = idx >> 8, col = idx & 255;
            Wt_bf[col * FIN + k] = f2bf(W1[k * FH + col]);
        }
        return;
    }
    __shared__ int lcnt[DPW];
    const int p  = blockIdx.x >> 6;
    const int r  = blockIdx.x & 63;
    const int lo = p * DPW;
    for (int i = t; i < DPW; i += 1024) lcnt[i] = 0;
    __syncthreads();
    const int ebase = r * EPW, eend = ebase + EPW;
    for (int e0 = ebase + t * 4; e0 < eend; e0 += 4096) {
        int4 dv4 = *(const int4*)&ei[E_RAW + e0];   // coalesced 16B
#pragma unroll
        for (int k = 0; k < 4; k++) {
            unsigned rel = (unsigned)((&dv4.x)[k] - lo);
            if (rel < DPW) atomicAdd(&lcnt[rel], 1);   // LDS, no return
        }
    }
    __syncthreads();
    for (int i = t; i < DPW; i += 1024)
        pcnt16[r * NN + lo + i] = (unsigned short)lcnt[i];
}

// ---------------------------------------------------------------------------
// D2: FUSED offsets + gemm.
// ---------------------------------------------------------------------------
__global__ __launch_bounds__(256) void k_gx(const float* __restrict__ x,
                                            const unsigned short* __restrict__ Wt_bf,
                                            const float* __restrict__ att_src,
                                            const float* __restrict__ att_dst,
                                            const unsigned short* __restrict__ pcnt16,
                                            unsigned short* __restrict__ soff16,
                                            int* __restrict__ cnt,
                                            unsigned short* __restrict__ csr16,
                                            unsigned short* __restrict__ h1b,
                                            float* __restrict__ a_s,
                                            float* __restrict__ a_d)
{
    const int t = threadIdx.x;
    if (blockIdx.x < OFF_NB) {
        int d = blockIdx.x * 256 + t;
        if (d >= NN) return;
        int run = 1;                     // slot 0 = self loop
#pragma unroll
        for (int r = 0; r < R_REP; r++) {
            soff16[r * NN + d] = (unsigned short)run;
            run += pcnt16[r * NN + d];
        }
        cnt[d] = run;                    // clamped at use
        csr16[(size_t)d << 6] = (unsigned short)d;   // self-loop src
        return;
    }

    // ---------------- gemm path ----------------
    __shared__ unsigned short Sbuf[64 * 256];
    const int w    = t >> 6;
    const int lane = t & 63;
    const int li   = lane & 15;
    const int q8   = (lane >> 4) * 8;
    const int quad = lane >> 4;
    const int n0   = (blockIdx.x - OFF_NB) * 64;

    {
        const int node_l = t >> 2;
        const int k0 = (t & 3) * 32;
        int nn = n0 + node_l; if (nn >= NN) nn = NN - 1;
        const float* xp = &x[(size_t)nn * FIN + k0];
        unsigned short* xd = &Sbuf[node_l * 136 + k0];
#pragma unroll
        for (int i = 0; i < 8; i++) {
            float4 v = *(const float4*)&xp[i * 4];
            xd[i * 4 + 0] = f2bf(v.x);
            xd[i * 4 + 1] = f2bf(v.y);
            xd[i * 4 + 2] = f2bf(v.z);
            xd[i * 4 + 3] = f2bf(v.w);
        }
    }
    __syncthreads();

    f32x4 acc[4][4];
#pragma unroll
    for (int i = 0; i < 4; i++)
#pragma unroll
        for (int j = 0; j < 4; j++) acc[i][j] = (f32x4){0.f, 0.f, 0.f, 0.f};

#pragma unroll
    for (int kki = 0; kki < 4; kki++) {
        const int kk = kki * 32;
        s16x8 af[4], bf[4];
#pragma unroll
        for (int n16 = 0; n16 < 4; n16++) {
            int col = w * 64 + n16 * 16 + li;
            bf[n16] = *(const s16x8*)&Wt_bf[col * FIN + kk + q8];
        }
#pragma unroll
        for (int m16 = 0; m16 < 4; m16++)
            af[m16] = *(const s16x8*)&Sbuf[(m16 * 16 + li) * 136 + kk + q8];
#pragma unroll
        for (int m16 = 0; m16 < 4; m16++)
#pragma unroll
            for (int n16 = 0; n16 < 4; n16++)
                acc[m16][n16] = __builtin_amdgcn_mfma_f32_16x16x32_bf16(
                    af[m16], bf[n16], acc[m16][n16], 0, 0, 0);
    }

    // epilogue A: per-head attention logits
    {
        float as_c[4], ad_c[4];
#pragma unroll
        for (int n16 = 0; n16 < 4; n16++) {
            int col = w * 64 + n16 * 16 + li;
            as_c[n16] = att_src[col];
            ad_c[n16] = att_dst[col];
        }
#pragma unroll
        for (int m16 = 0; m16 < 4; m16++) {
            float ps[4], pd[4];
#pragma unroll
            for (int reg = 0; reg < 4; reg++) {
                float s = 0.f, d = 0.f;
#pragma unroll
                for (int n16 = 0; n16 < 4; n16++) {
                    s += acc[m16][n16][reg] * as_c[n16];
                    d += acc[m16][n16][reg] * ad_c[n16];
                }
                ps[reg] = s; pd[reg] = d;
            }
#pragma unroll
            for (int off = 1; off < 16; off <<= 1) {
#pragma unroll
                for (int reg = 0; reg < 4; reg++) {
                    ps[reg] += __shfl_xor(ps[reg], off);
                    pd[reg] += __shfl_xor(pd[reg], off);
                }
            }
            if (li == 0) {
#pragma unroll
                for (int reg = 0; reg < 4; reg++) {
                    int node = n0 + m16 * 16 + quad * 4 + reg;
                    if (node < NN) {
                        a_s[node * 4 + w] = ps[reg];
                        a_d[node * 4 + w] = pd[reg];
                    }
                }
            }
        }
    }

    // epilogue B: bf16 store via LDS round-trip
    __syncthreads();
#pragma unroll
    for (int m16 = 0; m16 < 4; m16++)
#pragma unroll
        for (int n16 = 0; n16 < 4; n16++)
#pragma unroll
            for (int reg = 0; reg < 4; reg++)
                Sbuf[(m16 * 16 + quad * 4 + reg) * FH + w * 64 + n16 * 16 + li] =
                    f2bf(acc[m16][n16][reg]);
    __syncthreads();
    {
        const int node_l = t >> 2;
        const int c0 = (t & 3) * 64;
        int node = n0 + node_l;
        if (node < NN) {
#pragma unroll
            for (int i = 0; i < 8; i++)
                *(uint4*)&h1b[(size_t)node * FH + c0 + i * 8] =
                    *(const uint4*)&Sbuf[node_l * FH + c0 + i * 8];
        }
    }
}

// ---------------------------------------------------------------------------
// D3: scatter into contiguous buckets (u16 payload).  Also zeroes the grid
// barrier word for D4 (stream order publishes it; each graph replay
// re-zeroes).  1024-thread WGs (R14 lesson: do NOT shrink).
// ---------------------------------------------------------------------------
__global__ __launch_bounds__(1024) void k_scat2(const int* __restrict__ ei,
                                                const unsigned short* __restrict__ soff16,
                                                unsigned short* __restrict__ csr16,
                                                int* __restrict__ bar)
{
    if (blockIdx.x == 0 && threadIdx.x == 0) *bar = 0;
    __shared__ int cur[DPW];
    const int t  = threadIdx.x;
    const int p  = blockIdx.x >> 6;
    const int r  = blockIdx.x & 63;
    const int lo = p * DPW;
    for (int i = t; i < DPW; i += 1024)
        cur[i] = soff16[r * NN + lo + i];
    __syncthreads();
    const int ebase = r * EPW, eend = ebase + EPW;
    for (int e0 = ebase + t * 4; e0 < eend; e0 += 4096) {
        int4 sv4 = *(const int4*)&ei[e0];           // coalesced 16B (src)
        int4 dv4 = *(const int4*)&ei[E_RAW + e0];   // coalesced 16B (dst)
#pragma unroll
        for (int k = 0; k < 4; k++) {
            int d = (&dv4.x)[k];
            unsigned rel = (unsigned)(d - lo);
            if (rel < DPW) {
                int pos = atomicAdd(&cur[rel], 1);  // LDS ds_add_rtn
                if (pos < BCAP)
                    csr16[((size_t)d << 6) + pos] = (unsigned short)(&sv4.x)[k];
            }
        }
    }
}

// ---------------------------------------------------------------------------
// D4: FUSED agg1 + agg2 with a manual resident-grid barrier (R24 fix).
// 2048 blocks x 256 thr, LB(256,8): 8 blocks/CU x 256 CU = all co-resident
// by construction (R23 confirmed: correct result, 98% occupancy).  Spin is
// now benign: release-add on arrival; RELAXED polls (no per-poll L1
// invalidate) every s_sleep(127) ~ 8k cycles -> ~0.25 polls/cycle grid-wide
// (R23's s_sleep(4)+ACQUIRE was ~8/cycle on one line = fabric storm,
// 900us).  syncthreads+threadfence after the loop is the acquire for all
// threads.  ~17ms timeout escape -> visible wrong answer, never a hang.
// Phase 1 = EXACT R20 agg1 body grid-strided (12500*4 == NN).
// Phase 2 = EXACT agg2 grid-strided (3125*16 == NN).
// ---------------------------------------------------------------------------
__global__ __launch_bounds__(256, 8) void k_agg(const int* __restrict__ cnt,
                                                const unsigned short* __restrict__ csr16,
                                                const float* __restrict__ a_s1,
                                                const float* __restrict__ a_d1,
                                                const unsigned short* __restrict__ h1b,
                                                const float* __restrict__ b1,
                                                const float* __restrict__ W2,
                                                const float* __restrict__ att_src2,
                                                const float* __restrict__ att_dst2,
                                                float4* __restrict__ nd4,
                                                const float* __restrict__ b2,
                                                float* __restrict__ out,
                                                int* __restrict__ bar)
{
    const int t = threadIdx.x;

    // ---- phase 1: layer-1 aggregation (v1 body, grid-stride) ----
    for (int wk = blockIdx.x; wk < NN / 4; wk += AGG_GRID) {
        const int lane = t & 63;
        const int n = wk * 4 + (t >> 6);         // < NN always (12500*4==NN)
        int m = cnt[n]; if (m > BCAP) m = BCAP;
        const int h = lane >> 4;
        const float ad_h = a_d1[n * 4 + h];
        float acc0 = 0.f, acc1 = 0.f, acc2 = 0.f, acc3 = 0.f, z = 0.f;
        const unsigned short* sp = &csr16[(size_t)n << 6];
#pragma unroll 4
        for (int j = 0; j < m; j++) {
            int s = sp[j];                       // wave-uniform 2B
            float as_h = a_s1[s * 4 + h];
            float ex = __expf(leaky(as_h + ad_h));
            unsigned long long wv =
                *(const unsigned long long*)(h1b + (size_t)s * FH + lane * 4);
            unsigned lo = (unsigned)wv, hi = (unsigned)(wv >> 32);
            acc0 += __uint_as_float(lo << 16) * ex;
            acc1 += __uint_as_float(lo & 0xffff0000u) * ex;
            acc2 += __uint_as_float(hi << 16) * ex;
            acc3 += __uint_as_float(hi & 0xffff0000u) * ex;
            z += ex;
        }
        const int c0 = lane * 4;
        float4 bb = *(const float4*)&b1[c0];
        float v0 = acc0 / z + bb.x;
        float v1 = acc1 / z + bb.y;
        float v2 = acc2 / z + bb.z;
        float v3 = acc3 / z + bb.w;
        v0 = v0 > 0.f ? v0 : __expf(v0) - 1.f;   // ELU
        v1 = v1 > 0.f ? v1 : __expf(v1) - 1.f;
        v2 = v2 > 0.f ? v2 : __expf(v2) - 1.f;
        v3 = v3 > 0.f ? v3 : __expf(v3) - 1.f;
        float4 w2a = *(const float4*)&W2[c0 * 2];
        float4 w2b = *(const float4*)&W2[c0 * 2 + 4];
        float s0 = v0 * w2a.x + v1 * w2a.z + v2 * w2b.x + v3 * w2b.z;
        float s1 = v0 * w2a.y + v1 * w2a.w + v2 * w2b.y + v3 * w2b.w;
#pragma unroll
        for (int off = 32; off; off >>= 1) {
            s0 += __shfl_xor(s0, off);
            s1 += __shfl_xor(s1, off);
        }
        if (lane == 0) {
            float4 nd;
            nd.x = s0; nd.y = s1;
            nd.z = s0 * att_src2[0] + s1 * att_src2[1];
            nd.w = s0 * att_dst2[0] + s1 * att_dst2[1];
            nd4[n] = nd;
        }
    }

    // ---- resident-grid barrier: release add, relaxed low-rate polls ----
    __threadfence();
    __syncthreads();
    if (t == 0) {
        __hip_atomic_fetch_add(bar, 1, __ATOMIC_RELEASE,
                               __HIP_MEMORY_SCOPE_AGENT);
        long long t0 = clock64();
        while (__hip_atomic_load(bar, __ATOMIC_RELAXED,
                                 __HIP_MEMORY_SCOPE_AGENT) < AGG_GRID) {
            __builtin_amdgcn_s_sleep(127);       // ~8k cycles between polls
            if (clock64() - t0 > (42LL << 20)) break;   // ~17ms anti-hang
        }
    }
    __syncthreads();
    __threadfence();                             // acquire for all threads

    // ---- phase 2: layer-2 aggregation (16 lanes per dst, grid-stride) ----
    for (int u = blockIdx.x; u < NN / 16; u += AGG_GRID) {
        const int l = t & 15;
        const int n = u * 16 + (t >> 4);         // < NN always (3125*16==NN)
        int m = cnt[n]; if (m > BCAP) m = BCAP;
        const unsigned short* sp = &csr16[(size_t)n << 6];
        const float ad = nd4[n].w;
        float z = 0.f, a0 = 0.f, a1 = 0.f;
        for (int j = l; j < m; j += 16) {
            int s = sp[j];
            float4 f = nd4[s];
            float ex = __expf(leaky(f.z + ad));
            z  += ex;
            a0 += f.x * ex;
            a1 += f.y * ex;
        }
#pragma unroll
        for (int off = 8; off; off >>= 1) {
            z  += __shfl_xor(z, off);
            a0 += __shfl_xor(a0, off);
            a1 += __shfl_xor(a1, off);
        }
        if (l == 0) {
            out[n * 2 + 0] = a0 / z + b2[0];
            out[n * 2 + 1] = a1 / z + b2[1];
        }
    }
}

extern "C" void kernel_launch(void* const* d_in, const int* in_sizes, int n_in,
                              void* d_out, int out_size, void* d_ws, size_t ws_size,
                              hipStream_t stream)
{
    const float* x        = (const float*)d_in[0];
    const int*   ei       = (const int*)d_in[1];
    const float* W1       = (const float*)d_in[2];
    const float* att_src1 = (const float*)d_in[3];
    const float* att_dst1 = (const float*)d_in[4];
    const float* b1       = (const float*)d_in[5];
    const float* W2       = (const float*)d_in[6];
    const float* att_src2 = (const float*)d_in[7];
    const float* att_dst2 = (const float*)d_in[8];
    const float* b2       = (const float*)d_in[9];
    float* out = (float*)d_out;

    // --- workspace layout (all regions 16B aligned) ---
    unsigned short* csr16 = (unsigned short*)d_ws;           // NN*64*2 = 6.4 MB
    unsigned short* h1b   = csr16 + (size_t)NN * 64;         // 25.6 MB
    unsigned short* Wt_bf = h1b + (size_t)NN * FH;           // 64 KB
    unsigned short* pcnt16 = Wt_bf + FH * FIN;               // NN*64*2 = 6.4 MB
    unsigned short* soff16 = pcnt16 + (size_t)NN * R_REP;    // 6.4 MB
    int*    cnt   = (int*)(soff16 + (size_t)NN * R_REP);     // 200 KB
    float*  a_s1  = (float*)(cnt + NN);                      // 800 KB
    float*  a_d1  = a_s1 + (size_t)NN * 4;                   // 800 KB
    float4* nd4   = (float4*)(a_d1 + (size_t)NN * 4);        // 800 KB
    int*    bar   = (int*)(nd4 + NN);                        // 16 B

    k_count<<<CNT_WGS + PREP_WGS, 1024, 0, stream>>>(ei, W1, Wt_bf, pcnt16);
    k_gx<<<OFF_NB + GEMM_NB, 256, 0, stream>>>(x, Wt_bf, att_src1, att_dst1,
                                               pcnt16, soff16, cnt, csr16,
                                               h1b, a_s1, a_d1);
    k_scat2<<<CNT_WGS, 1024, 0, stream>>>(ei, soff16, csr16, bar);
    k_agg<<<AGG_GRID, 256, 0, stream>>>(cnt, csr16, a_s1, a_d1, h1b,
                                        b1, W2, att_src2, att_dst2, nd4,
                                        b2, out, bar);
}

// Round 10
// 225.582 us; speedup vs baseline: 4.3369x; 3.2700x over previous
//
#include <hip/hip_runtime.h>

#define NN     50000
#define E_RAW  800000
#define ETOT   (E_RAW + NN)   /* 850000: edges + self loops */
#define FIN    128
#define FH     256            /* HEADS*HID */
#define NEG    0.2f
#define BCAP   64             /* bucket capacity; P(deg>64) ~ 1e-18 */

/* Counting-sort CSR build.  R9: global atomics cap ~11 ops/ns -> LDS
   histograms.  R14: scatter needs its own 1024-thr dispatch.  R19: agg1
   codegen is fragile -- touch nothing in its body.  R21: cooperative
   LAUNCH API kills the harness.  R23/R24: manual resident-grid barrier is
   correct but collapses issue rate 9x (VALUBusy 63%->7%) -- fusion arc
   permanently dead; 5-dispatch skeleton is final.
   R25: soff[] dropped -- each scatter WG derives its own cursors by
   prefixing pcnt over replicas rr<r for its slice (L2-hot, coalesced);
   k_gx offset blocks shrink to cnt-only.  P_PART=8/R_REP=32 (R20 config,
   measured == R22's 4/64) keeps the prefix cheap. */
#define P_PART 8
#define DPW    6250             /* dsts per partition, 25KB LDS */
#define R_REP  32
#define EPW    (E_RAW / R_REP)  /* 25000 edges per replica */
#define CNT_WGS (P_PART * R_REP) /* 256 */
#define PREP_WGS 8              /* W1 transpose: 8 x 4096 elems */
#define OFF_NB  ((NN + 255) / 256)   /* 196 offset blocks */
#define GEMM_NB ((NN + 63) / 64)     /* 782 gemm blocks */

typedef __attribute__((ext_vector_type(8))) short s16x8;
typedef __attribute__((ext_vector_type(4))) float f32x4;

static __device__ __forceinline__ float leaky(float v) { return v > 0.f ? v : NEG * v; }

// RNE float->bf16
static __device__ __forceinline__ unsigned short f2bf(float f) {
    unsigned u = __float_as_uint(f);
    unsigned r = u + 0x7fffu + ((u >> 16) & 1u);
    return (unsigned short)(r >> 16);
}

// ---------------------------------------------------------------------------
// D1: count pass + W1 prep.
// blocks [0,256): WG(p=b>>5, r=b&31) histograms dst stream slice r into LDS
//   (non-returning ds_add), writes pcnt16[r*NN + d] coalesced.
// blocks [256,264): W1 fp32 [k][col] -> bf16 Wt_bf[col][k] (strided).
// ---------------------------------------------------------------------------
__global__ __launch_bounds__(1024) void k_count(const int* __restrict__ ei,
                                                const float* __restrict__ W1,
                                                unsigned short* __restrict__ Wt_bf,
                                                unsigned short* __restrict__ pcnt16)
{
    const int t = threadIdx.x;
    if (blockIdx.x >= CNT_WGS) {
        const int base = (blockIdx.x - CNT_WGS) * 4096;
        for (int i = t; i < 4096; i += 1024) {
            int idx = base + i;                 // < 32768
            int k = idx >> 8, col = idx & 255;
            Wt_bf[col * FIN + k] = f2bf(W1[k * FH + col]);
        }
        return;
    }
    __shared__ int lcnt[DPW];
    const int p  = blockIdx.x >> 5;
    const int r  = blockIdx.x & 31;
    const int lo = p * DPW;
    for (int i = t; i < DPW; i += 1024) lcnt[i] = 0;
    __syncthreads();
    const int ebase = r * EPW, eend = ebase + EPW;
    for (int e0 = ebase + t * 4; e0 < eend; e0 += 4096) {
        int4 dv4 = *(const int4*)&ei[E_RAW + e0];   // coalesced 16B
#pragma unroll
        for (int k = 0; k < 4; k++) {
            unsigned rel = (unsigned)((&dv4.x)[k] - lo);
            if (rel < DPW) atomicAdd(&lcnt[rel], 1);   // LDS, no return
        }
    }
    __syncthreads();
    for (int i = t; i < DPW; i += 1024)
        pcnt16[r * NN + lo + i] = (unsigned short)lcnt[i];
}

// ---------------------------------------------------------------------------
// D2: FUSED cnt + gemm.
// blocks [0,196): cnt[d] = 1 + sum_r pcnt[r][d] (slot 0 = self loop);
//   writes the self-loop src.  (soff dropped in R25: scatter WGs derive
//   their own cursors from pcnt.)
// blocks [196,978): h1 = x@W1 via MFMA bf16.
// ---------------------------------------------------------------------------
__global__ __launch_bounds__(256) void k_gx(const float* __restrict__ x,
                                            const unsigned short* __restrict__ Wt_bf,
                                            const float* __restrict__ att_src,
                                            const float* __restrict__ att_dst,
                                            const unsigned short* __restrict__ pcnt16,
                                            int* __restrict__ cnt,
                                            unsigned short* __restrict__ csr16,
                                            unsigned short* __restrict__ h1b,
                                            float* __restrict__ a_s,
                                            float* __restrict__ a_d)
{
    const int t = threadIdx.x;
    if (blockIdx.x < OFF_NB) {
        int d = blockIdx.x * 256 + t;
        if (d >= NN) return;
        int run = 1;                     // slot 0 = self loop
#pragma unroll
        for (int r = 0; r < R_REP; r++)
            run += pcnt16[r * NN + d];
        cnt[d] = run;                    // clamped at use
        csr16[(size_t)d << 6] = (unsigned short)d;   // self-loop src
        return;
    }

    // ---------------- gemm path ----------------
    __shared__ unsigned short Sbuf[64 * 256];
    const int w    = t >> 6;
    const int lane = t & 63;
    const int li   = lane & 15;
    const int q8   = (lane >> 4) * 8;
    const int quad = lane >> 4;
    const int n0   = (blockIdx.x - OFF_NB) * 64;

    {
        const int node_l = t >> 2;
        const int k0 = (t & 3) * 32;
        int nn = n0 + node_l; if (nn >= NN) nn = NN - 1;
        const float* xp = &x[(size_t)nn * FIN + k0];
        unsigned short* xd = &Sbuf[node_l * 136 + k0];
#pragma unroll
        for (int i = 0; i < 8; i++) {
            float4 v = *(const float4*)&xp[i * 4];
            xd[i * 4 + 0] = f2bf(v.x);
            xd[i * 4 + 1] = f2bf(v.y);
            xd[i * 4 + 2] = f2bf(v.z);
            xd[i * 4 + 3] = f2bf(v.w);
        }
    }
    __syncthreads();

    f32x4 acc[4][4];
#pragma unroll
    for (int i = 0; i < 4; i++)
#pragma unroll
        for (int j = 0; j < 4; j++) acc[i][j] = (f32x4){0.f, 0.f, 0.f, 0.f};

#pragma unroll
    for (int kki = 0; kki < 4; kki++) {
        const int kk = kki * 32;
        s16x8 af[4], bf[4];
#pragma unroll
        for (int n16 = 0; n16 < 4; n16++) {
            int col = w * 64 + n16 * 16 + li;
            bf[n16] = *(const s16x8*)&Wt_bf[col * FIN + kk + q8];
        }
#pragma unroll
        for (int m16 = 0; m16 < 4; m16++)
            af[m16] = *(const s16x8*)&Sbuf[(m16 * 16 + li) * 136 + kk + q8];
#pragma unroll
        for (int m16 = 0; m16 < 4; m16++)
#pragma unroll
            for (int n16 = 0; n16 < 4; n16++)
                acc[m16][n16] = __builtin_amdgcn_mfma_f32_16x16x32_bf16(
                    af[m16], bf[n16], acc[m16][n16], 0, 0, 0);
    }

    // epilogue A: per-head attention logits
    {
        float as_c[4], ad_c[4];
#pragma unroll
        for (int n16 = 0; n16 < 4; n16++) {
            int col = w * 64 + n16 * 16 + li;
            as_c[n16] = att_src[col];
            ad_c[n16] = att_dst[col];
        }
#pragma unroll
        for (int m16 = 0; m16 < 4; m16++) {
            float ps[4], pd[4];
#pragma unroll
            for (int reg = 0; reg < 4; reg++) {
                float s = 0.f, d = 0.f;
#pragma unroll
                for (int n16 = 0; n16 < 4; n16++) {
                    s += acc[m16][n16][reg] * as_c[n16];
                    d += acc[m16][n16][reg] * ad_c[n16];
                }
                ps[reg] = s; pd[reg] = d;
            }
#pragma unroll
            for (int off = 1; off < 16; off <<= 1) {
#pragma unroll
                for (int reg = 0; reg < 4; reg++) {
                    ps[reg] += __shfl_xor(ps[reg], off);
                    pd[reg] += __shfl_xor(pd[reg], off);
                }
            }
            if (li == 0) {
#pragma unroll
                for (int reg = 0; reg < 4; reg++) {
                    int node = n0 + m16 * 16 + quad * 4 + reg;
                    if (node < NN) {
                        a_s[node * 4 + w] = ps[reg];
                        a_d[node * 4 + w] = pd[reg];
                    }
                }
            }
        }
    }

    // epilogue B: bf16 store via LDS round-trip
    __syncthreads();
#pragma unroll
    for (int m16 = 0; m16 < 4; m16++)
#pragma unroll
        for (int n16 = 0; n16 < 4; n16++)
#pragma unroll
            for (int reg = 0; reg < 4; reg++)
                Sbuf[(m16 * 16 + quad * 4 + reg) * FH + w * 64 + n16 * 16 + li] =
                    f2bf(acc[m16][n16][reg]);
    __syncthreads();
    {
        const int node_l = t >> 2;
        const int c0 = (t & 3) * 64;
        int node = n0 + node_l;
        if (node < NN) {
#pragma unroll
            for (int i = 0; i < 8; i++)
                *(uint4*)&h1b[(size_t)node * FH + c0 + i * 8] =
                    *(const uint4*)&Sbuf[node_l * FH + c0 + i * 8];
        }
    }
}

// ---------------------------------------------------------------------------
// D3: scatter into contiguous buckets (u16 payload).  R25: WG(p,r) computes
// its own cursors from pcnt (prefix over replicas rr<r for its slice --
// coalesced u16 reads of L2-hot pcnt; r=0 skips).  Replica order preserved
// (cursor = 1 + sum_{rr<r} pcnt[rr][d], identical to the old soff).
// 1024-thread WGs (R14 lesson: do NOT shrink).
// ---------------------------------------------------------------------------
__global__ __launch_bounds__(1024) void k_scat2(const int* __restrict__ ei,
                                                const unsigned short* __restrict__ pcnt16,
                                                unsigned short* __restrict__ csr16)
{
    __shared__ int cur[DPW];
    const int t  = threadIdx.x;
    const int p  = blockIdx.x >> 5;
    const int r  = blockIdx.x & 31;
    const int lo = p * DPW;
    for (int i = t; i < DPW; i += 1024) {
        int run = 1;                         // slot 0 = self loop
        for (int rr = 0; rr < r; rr++)       // r uniform per-WG
            run += pcnt16[rr * NN + lo + i];
        cur[i] = run;
    }
    __syncthreads();
    const int ebase = r * EPW, eend = ebase + EPW;
    for (int e0 = ebase + t * 4; e0 < eend; e0 += 4096) {
        int4 sv4 = *(const int4*)&ei[e0];           // coalesced 16B (src)
        int4 dv4 = *(const int4*)&ei[E_RAW + e0];   // coalesced 16B (dst)
#pragma unroll
        for (int k = 0; k < 4; k++) {
            int d = (&dv4.x)[k];
            unsigned rel = (unsigned)(d - lo);
            if (rel < DPW) {
                int pos = atomicAdd(&cur[rel], 1);  // LDS ds_add_rtn
                if (pos < BCAP)
                    csr16[((size_t)d << 6) + pos] = (unsigned short)(&sv4.x)[k];
            }
        }
    }
}

// ---------------------------------------------------------------------------
// D4: layer-1 aggregation -- EXACT R20 body (66 us, 3.22 TB/s, VGPR 24:
// the empirical optimum across v1-v5 + two fusion attempts).  Untouched.
// FUSED: /z, +b1, ELU, W2 projection, layer-2 logits -> nd4.
// ---------------------------------------------------------------------------
__global__ __launch_bounds__(256) void k_agg1(const int* __restrict__ cnt,
                                              const unsigned short* __restrict__ csr16,
                                              const float* __restrict__ a_s1,
                                              const float* __restrict__ a_d1,
                                              const unsigned short* __restrict__ h1b,
                                              const float* __restrict__ b1,
                                              const float* __restrict__ W2,
                                              const float* __restrict__ att_src2,
                                              const float* __restrict__ att_dst2,
                                              float4* __restrict__ nd4)
{
    const int lane = threadIdx.x & 63;
    const int n = blockIdx.x * 4 + (threadIdx.x >> 6);
    if (n >= NN) return;
    int m = cnt[n]; if (m > BCAP) m = BCAP;
    const int h = lane >> 4;
    const float ad_h = a_d1[n * 4 + h];
    float acc0 = 0.f, acc1 = 0.f, acc2 = 0.f, acc3 = 0.f, z = 0.f;
    const unsigned short* sp = &csr16[(size_t)n << 6];
#pragma unroll 4
    for (int j = 0; j < m; j++) {
        int s = sp[j];                           // wave-uniform 2B
        float as_h = a_s1[s * 4 + h];
        float ex = __expf(leaky(as_h + ad_h));
        unsigned long long wv =
            *(const unsigned long long*)(h1b + (size_t)s * FH + lane * 4);
        unsigned lo = (unsigned)wv, hi = (unsigned)(wv >> 32);
        acc0 += __uint_as_float(lo << 16) * ex;
        acc1 += __uint_as_float(lo & 0xffff0000u) * ex;
        acc2 += __uint_as_float(hi << 16) * ex;
        acc3 += __uint_as_float(hi & 0xffff0000u) * ex;
        z += ex;
    }
    const int c0 = lane * 4;
    float4 bb = *(const float4*)&b1[c0];
    float v0 = acc0 / z + bb.x;
    float v1 = acc1 / z + bb.y;
    float v2 = acc2 / z + bb.z;
    float v3 = acc3 / z + bb.w;
    v0 = v0 > 0.f ? v0 : __expf(v0) - 1.f;   // ELU
    v1 = v1 > 0.f ? v1 : __expf(v1) - 1.f;
    v2 = v2 > 0.f ? v2 : __expf(v2) - 1.f;
    v3 = v3 > 0.f ? v3 : __expf(v3) - 1.f;
    float4 w2a = *(const float4*)&W2[c0 * 2];
    float4 w2b = *(const float4*)&W2[c0 * 2 + 4];
    float s0 = v0 * w2a.x + v1 * w2a.z + v2 * w2b.x + v3 * w2b.z;
    float s1 = v0 * w2a.y + v1 * w2a.w + v2 * w2b.y + v3 * w2b.w;
#pragma unroll
    for (int off = 32; off; off >>= 1) {
        s0 += __shfl_xor(s0, off);
        s1 += __shfl_xor(s1, off);
    }
    if (lane == 0) {
        float4 nd;
        nd.x = s0; nd.y = s1;
        nd.z = s0 * att_src2[0] + s1 * att_src2[1];
        nd.w = s0 * att_dst2[0] + s1 * att_dst2[1];
        nd4[n] = nd;
    }
}

// ---------------------------------------------------------------------------
// D5: layer-2 aggregation, 16 lanes per dst, contiguous u16 bucket; writes
// d_out.  EXACT R20 body.
// ---------------------------------------------------------------------------
__global__ __launch_bounds__(256) void k_agg2(const int* __restrict__ cnt,
                                              const unsigned short* __restrict__ csr16,
                                              const float4* __restrict__ nd4,
                                              const float* __restrict__ b2,
                                              float* __restrict__ out)
{
    const int l = threadIdx.x & 15;
    const int n = blockIdx.x * 16 + (threadIdx.x >> 4);
    if (n >= NN) return;
    int m = cnt[n]; if (m > BCAP) m = BCAP;
    const unsigned short* sp = &csr16[(size_t)n << 6];
    const float ad = nd4[n].w;
    float z = 0.f, a0 = 0.f, a1 = 0.f;
    for (int j = l; j < m; j += 16) {
        int s = sp[j];
        float4 f = nd4[s];
        float ex = __expf(leaky(f.z + ad));
        z  += ex;
        a0 += f.x * ex;
        a1 += f.y * ex;
    }
#pragma unroll
    for (int off = 8; off; off >>= 1) {
        z  += __shfl_xor(z, off);
        a0 += __shfl_xor(a0, off);
        a1 += __shfl_xor(a1, off);
    }
    if (l == 0) {
        out[n * 2 + 0] = a0 / z + b2[0];
        out[n * 2 + 1] = a1 / z + b2[1];
    }
}

extern "C" void kernel_launch(void* const* d_in, const int* in_sizes, int n_in,
                              void* d_out, int out_size, void* d_ws, size_t ws_size,
                              hipStream_t stream)
{
    const float* x        = (const float*)d_in[0];
    const int*   ei       = (const int*)d_in[1];
    const float* W1       = (const float*)d_in[2];
    const float* att_src1 = (const float*)d_in[3];
    const float* att_dst1 = (const float*)d_in[4];
    const float* b1       = (const float*)d_in[5];
    const float* W2       = (const float*)d_in[6];
    const float* att_src2 = (const float*)d_in[7];
    const float* att_dst2 = (const float*)d_in[8];
    const float* b2       = (const float*)d_in[9];
    float* out = (float*)d_out;

    // --- workspace layout (all regions 16B aligned) ---
    unsigned short* csr16 = (unsigned short*)d_ws;           // NN*64*2 = 6.4 MB
    unsigned short* h1b   = csr16 + (size_t)NN * 64;         // 25.6 MB
    unsigned short* Wt_bf = h1b + (size_t)NN * FH;           // 64 KB
    unsigned short* pcnt16 = Wt_bf + FH * FIN;               // NN*32*2 = 3.2 MB
    int*    cnt   = (int*)(pcnt16 + (size_t)NN * R_REP);     // 200 KB
    float*  a_s1  = (float*)(cnt + NN);                      // 800 KB
    float*  a_d1  = a_s1 + (size_t)NN * 4;                   // 800 KB
    float4* nd4   = (float4*)(a_d1 + (size_t)NN * 4);        // 800 KB

    k_count<<<CNT_WGS + PREP_WGS, 1024, 0, stream>>>(ei, W1, Wt_bf, pcnt16);
    k_gx<<<OFF_NB + GEMM_NB, 256, 0, stream>>>(x, Wt_bf, att_src1, att_dst1,
                                               pcnt16, cnt, csr16,
                                               h1b, a_s1, a_d1);
    k_scat2<<<CNT_WGS, 1024, 0, stream>>>(ei, pcnt16, csr16);
    k_agg1<<<(NN + 3) / 4, 256, 0, stream>>>(cnt, csr16, a_s1, a_d1, h1b,
                                             b1, W2, att_src2, att_dst2, nd4);
    k_agg2<<<(NN + 15) / 16, 256, 0, stream>>>(cnt, csr16, nd4, b2, out);
}

// Round 12
// 202.175 us; speedup vs baseline: 4.8390x; 1.1158x over previous
//
#include <hip/hip_runtime.h>

#define NN     50000
#define E_RAW  800000
#define ETOT   (E_RAW + NN)   /* 850000: edges + self loops */
#define FIN    128
#define FH     256            /* HEADS*HID */
#define NEG    0.2f
#define BCAP   64             /* bucket capacity; P(deg>64) ~ 1e-18 */

/* FINAL (R27 = R20 verbatim, the best-measured configuration: 201.7 us,
   harness-verified twice; R26's container failure was infra flake -- this
   exact source has no coop launch / barrier / novel API).
   Session ledger:
   - k_agg1 (66 us, 3.22 TB/s, FETCH 207 MB): random 512B-row gather at its
     fabric ceiling.  v1 structure (1 wave/dst, one full row per
     instruction, VGPR addressing, 50k waves) beat every restructure:
     subgroup splits (R16), channel-split+XCD pinning (R17), scalar
     addressing (R18), asm exp + unroll-8 (R19, VGPR 24->16 codegen trap),
     persistent fused forms (R23/24).
   - FETCH 207 MB = 8 XCDs x ~26 MB table: per-XCD compulsory fill; only
     lever left is row-byte compression (fp8) -- rejected, absmax is at
     0.00390625 already.
   - Non-agg1 ~135 us: invariant to scan-byte halving (R22), u16 widths
     (R20), soff removal (R25: serial prefix chain, +24 us).  Dispatch
     fusion: coop API kills harness (R21); manual resident-grid barrier
     collapses issue rate 9x (R23/24).  5-dispatch skeleton is final. */
#define P_PART 8
#define DPW    6250             /* dsts per partition, 25KB LDS */
#define R_REP  32
#define EPW    (E_RAW / R_REP)  /* 25000 edges per replica */
#define CNT_WGS (P_PART * R_REP) /* 256 */
#define PREP_WGS 8              /* W1 transpose: 8 x 4096 elems */
#define OFF_NB  ((NN + 255) / 256)   /* 196 offset blocks */
#define GEMM_NB ((NN + 63) / 64)     /* 782 gemm blocks */

typedef __attribute__((ext_vector_type(8))) short s16x8;
typedef __attribute__((ext_vector_type(4))) float f32x4;

static __device__ __forceinline__ float leaky(float v) { return v > 0.f ? v : NEG * v; }

// RNE float->bf16
static __device__ __forceinline__ unsigned short f2bf(float f) {
    unsigned u = __float_as_uint(f);
    unsigned r = u + 0x7fffu + ((u >> 16) & 1u);
    return (unsigned short)(r >> 16);
}

// ---------------------------------------------------------------------------
// D1: count pass + W1 prep.
// blocks [0,256): WG(p=b>>5, r=b&31) histograms dst stream slice r into LDS
//   (non-returning ds_add), writes pcnt16[r*NN + d] coalesced.
// blocks [256,264): W1 fp32 [k][col] -> bf16 Wt_bf[col][k] (strided).
// ---------------------------------------------------------------------------
__global__ __launch_bounds__(1024) void k_count(const int* __restrict__ ei,
                                                const float* __restrict__ W1,
                                                unsigned short* __restrict__ Wt_bf,
                                                unsigned short* __restrict__ pcnt16)
{
    const int t = threadIdx.x;
    if (blockIdx.x >= CNT_WGS) {
        const int base = (blockIdx.x - CNT_WGS) * 4096;
        for (int i = t; i < 4096; i += 1024) {
            int idx = base + i;                 // < 32768
            int k = idx >> 8, col = idx & 255;
            Wt_bf[col * FIN + k] = f2bf(W1[k * FH + col]);
        }
        return;
    }
    __shared__ int lcnt[DPW];
    const int p  = blockIdx.x >> 5;
    const int r  = blockIdx.x & 31;
    const int lo = p * DPW;
    for (int i = t; i < DPW; i += 1024) lcnt[i] = 0;
    __syncthreads();
    const int ebase = r * EPW, eend = ebase + EPW;
    for (int e0 = ebase + t * 4; e0 < eend; e0 += 4096) {
        int4 dv4 = *(const int4*)&ei[E_RAW + e0];   // coalesced 16B
#pragma unroll
        for (int k = 0; k < 4; k++) {
            unsigned rel = (unsigned)((&dv4.x)[k] - lo);
            if (rel < DPW) atomicAdd(&lcnt[rel], 1);   // LDS, no return
        }
    }
    __syncthreads();
    for (int i = t; i < DPW; i += 1024)
        pcnt16[r * NN + lo + i] = (unsigned short)lcnt[i];
}

// ---------------------------------------------------------------------------
// D2: FUSED offsets + gemm.
// blocks [0,196): per-dst prefix over 32 partial counts -> soff16[r*NN+d];
//   slot 0 reserved for self-loop (csr16[d*64]=d); cnt[d]=1+sum.
// blocks [196,978): h1 = x@W1 via MFMA bf16.
// ---------------------------------------------------------------------------
__global__ __launch_bounds__(256) void k_gx(const float* __restrict__ x,
                                            const unsigned short* __restrict__ Wt_bf,
                                            const float* __restrict__ att_src,
                                            const float* __restrict__ att_dst,
                                            const unsigned short* __restrict__ pcnt16,
                                            unsigned short* __restrict__ soff16,
                                            int* __restrict__ cnt,
                                            unsigned short* __restrict__ csr16,
                                            unsigned short* __restrict__ h1b,
                                            float* __restrict__ a_s,
                                            float* __restrict__ a_d)
{
    const int t = threadIdx.x;
    if (blockIdx.x < OFF_NB) {
        int d = blockIdx.x * 256 + t;
        if (d >= NN) return;
        int run = 1;                     // slot 0 = self loop
#pragma unroll
        for (int r = 0; r < R_REP; r++) {
            soff16[r * NN + d] = (unsigned short)run;
            run += pcnt16[r * NN + d];
        }
        cnt[d] = run;                    // clamped at use
        csr16[(size_t)d << 6] = (unsigned short)d;   // self-loop src
        return;
    }

    // ---------------- gemm path ----------------
    __shared__ unsigned short Sbuf[64 * 256];
    const int w    = t >> 6;
    const int lane = t & 63;
    const int li   = lane & 15;
    const int q8   = (lane >> 4) * 8;
    const int quad = lane >> 4;
    const int n0   = (blockIdx.x - OFF_NB) * 64;

    {
        const int node_l = t >> 2;
        const int k0 = (t & 3) * 32;
        int nn = n0 + node_l; if (nn >= NN) nn = NN - 1;
        const float* xp = &x[(size_t)nn * FIN + k0];
        unsigned short* xd = &Sbuf[node_l * 136 + k0];
#pragma unroll
        for (int i = 0; i < 8; i++) {
            float4 v = *(const float4*)&xp[i * 4];
            xd[i * 4 + 0] = f2bf(v.x);
            xd[i * 4 + 1] = f2bf(v.y);
            xd[i * 4 + 2] = f2bf(v.z);
            xd[i * 4 + 3] = f2bf(v.w);
        }
    }
    __syncthreads();

    f32x4 acc[4][4];
#pragma unroll
    for (int i = 0; i < 4; i++)
#pragma unroll
        for (int j = 0; j < 4; j++) acc[i][j] = (f32x4){0.f, 0.f, 0.f, 0.f};

#pragma unroll
    for (int kki = 0; kki < 4; kki++) {
        const int kk = kki * 32;
        s16x8 af[4], bf[4];
#pragma unroll
        for (int n16 = 0; n16 < 4; n16++) {
            int col = w * 64 + n16 * 16 + li;
            bf[n16] = *(const s16x8*)&Wt_bf[col * FIN + kk + q8];
        }
#pragma unroll
        for (int m16 = 0; m16 < 4; m16++)
            af[m16] = *(const s16x8*)&Sbuf[(m16 * 16 + li) * 136 + kk + q8];
#pragma unroll
        for (int m16 = 0; m16 < 4; m16++)
#pragma unroll
            for (int n16 = 0; n16 < 4; n16++)
                acc[m16][n16] = __builtin_amdgcn_mfma_f32_16x16x32_bf16(
                    af[m16], bf[n16], acc[m16][n16], 0, 0, 0);
    }

    // epilogue A: per-head attention logits
    {
        float as_c[4], ad_c[4];
#pragma unroll
        for (int n16 = 0; n16 < 4; n16++) {
            int col = w * 64 + n16 * 16 + li;
            as_c[n16] = att_src[col];
            ad_c[n16] = att_dst[col];
        }
#pragma unroll
        for (int m16 = 0; m16 < 4; m16++) {
            float ps[4], pd[4];
#pragma unroll
            for (int reg = 0; reg < 4; reg++) {
                float s = 0.f, d = 0.f;
#pragma unroll
                for (int n16 = 0; n16 < 4; n16++) {
                    s += acc[m16][n16][reg] * as_c[n16];
                    d += acc[m16][n16][reg] * ad_c[n16];
                }
                ps[reg] = s; pd[reg] = d;
            }
#pragma unroll
            for (int off = 1; off < 16; off <<= 1) {
#pragma unroll
                for (int reg = 0; reg < 4; reg++) {
                    ps[reg] += __shfl_xor(ps[reg], off);
                    pd[reg] += __shfl_xor(pd[reg], off);
                }
            }
            if (li == 0) {
#pragma unroll
                for (int reg = 0; reg < 4; reg++) {
                    int node = n0 + m16 * 16 + quad * 4 + reg;
                    if (node < NN) {
                        a_s[node * 4 + w] = ps[reg];
                        a_d[node * 4 + w] = pd[reg];
                    }
                }
            }
        }
    }

    // epilogue B: bf16 store via LDS round-trip
    __syncthreads();
#pragma unroll
    for (int m16 = 0; m16 < 4; m16++)
#pragma unroll
        for (int n16 = 0; n16 < 4; n16++)
#pragma unroll
            for (int reg = 0; reg < 4; reg++)
                Sbuf[(m16 * 16 + quad * 4 + reg) * FH + w * 64 + n16 * 16 + li] =
                    f2bf(acc[m16][n16][reg]);
    __syncthreads();
    {
        const int node_l = t >> 2;
        const int c0 = (t & 3) * 64;
        int node = n0 + node_l;
        if (node < NN) {
#pragma unroll
            for (int i = 0; i < 8; i++)
                *(uint4*)&h1b[(size_t)node * FH + c0 + i * 8] =
                    *(const uint4*)&Sbuf[node_l * FH + c0 + i * 8];
        }
    }
}

// ---------------------------------------------------------------------------
// D3: scatter into contiguous buckets (u16 payload: src < 2^16; halves the
// random write-allocate footprint to 2 lines/bucket).  1024-thread WGs
// (R14 lesson: do NOT shrink).
// ---------------------------------------------------------------------------
__global__ __launch_bounds__(1024) void k_scat2(const int* __restrict__ ei,
                                                const unsigned short* __restrict__ soff16,
                                                unsigned short* __restrict__ csr16)
{
    __shared__ int cur[DPW];
    const int t  = threadIdx.x;
    const int p  = blockIdx.x >> 5;
    const int r  = blockIdx.x & 31;
    const int lo = p * DPW;
    for (int i = t; i < DPW; i += 1024)
        cur[i] = soff16[r * NN + lo + i];
    __syncthreads();
    const int ebase = r * EPW, eend = ebase + EPW;
    for (int e0 = ebase + t * 4; e0 < eend; e0 += 4096) {
        int4 sv4 = *(const int4*)&ei[e0];           // coalesced 16B (src)
        int4 dv4 = *(const int4*)&ei[E_RAW + e0];   // coalesced 16B (dst)
#pragma unroll
        for (int k = 0; k < 4; k++) {
            int d = (&dv4.x)[k];
            unsigned rel = (unsigned)(d - lo);
            if (rel < DPW) {
                int pos = atomicAdd(&cur[rel], 1);  // LDS ds_add_rtn
                if (pos < BCAP)
                    csr16[((size_t)d << 6) + pos] = (unsigned short)(&sv4.x)[k];
            }
        }
    }
}

// ---------------------------------------------------------------------------
// D4: layer-1 aggregation -- the v1 body (66 us, 3.22 TB/s, VGPR 24: the
// empirical optimum across five structural variants and two fusion
// attempts).  ONE wave per dst; lane l owns channels 4l..4l+3; 8B h1b
// gather + per-lane a_s1 + in-loop __expf; unroll 4; u16 bucket reads.
// FUSED: /z, +b1, ELU, W2 projection, layer-2 logits -> nd4.
// ---------------------------------------------------------------------------
__global__ __launch_bounds__(256) void k_agg1(const int* __restrict__ cnt,
                                              const unsigned short* __restrict__ csr16,
                                              const float* __restrict__ a_s1,
                                              const float* __restrict__ a_d1,
                                              const unsigned short* __restrict__ h1b,
                                              const float* __restrict__ b1,
                                              const float* __restrict__ W2,
                                              const float* __restrict__ att_src2,
                                              const float* __restrict__ att_dst2,
                                              float4* __restrict__ nd4)
{
    const int lane = threadIdx.x & 63;
    const int n = blockIdx.x * 4 + (threadIdx.x >> 6);
    if (n >= NN) return;
    int m = cnt[n]; if (m > BCAP) m = BCAP;
    const int h = lane >> 4;
    const float ad_h = a_d1[n * 4 + h];
    float acc0 = 0.f, acc1 = 0.f, acc2 = 0.f, acc3 = 0.f, z = 0.f;
    const unsigned short* sp = &csr16[(size_t)n << 6];
#pragma unroll 4
    for (int j = 0; j < m; j++) {
        int s = sp[j];                           // wave-uniform 2B
        float as_h = a_s1[s * 4 + h];
        float ex = __expf(leaky(as_h + ad_h));
        unsigned long long wv =
            *(const unsigned long long*)(h1b + (size_t)s * FH + lane * 4);
        unsigned lo = (unsigned)wv, hi = (unsigned)(wv >> 32);
        acc0 += __uint_as_float(lo << 16) * ex;
        acc1 += __uint_as_float(lo & 0xffff0000u) * ex;
        acc2 += __uint_as_float(hi << 16) * ex;
        acc3 += __uint_as_float(hi & 0xffff0000u) * ex;
        z += ex;
    }
    const int c0 = lane * 4;
    float4 bb = *(const float4*)&b1[c0];
    float v0 = acc0 / z + bb.x;
    float v1 = acc1 / z + bb.y;
    float v2 = acc2 / z + bb.z;
    float v3 = acc3 / z + bb.w;
    v0 = v0 > 0.f ? v0 : __expf(v0) - 1.f;   // ELU
    v1 = v1 > 0.f ? v1 : __expf(v1) - 1.f;
    v2 = v2 > 0.f ? v2 : __expf(v2) - 1.f;
    v3 = v3 > 0.f ? v3 : __expf(v3) - 1.f;
    float4 w2a = *(const float4*)&W2[c0 * 2];
    float4 w2b = *(const float4*)&W2[c0 * 2 + 4];
    float s0 = v0 * w2a.x + v1 * w2a.z + v2 * w2b.x + v3 * w2b.z;
    float s1 = v0 * w2a.y + v1 * w2a.w + v2 * w2b.y + v3 * w2b.w;
#pragma unroll
    for (int off = 32; off; off >>= 1) {
        s0 += __shfl_xor(s0, off);
        s1 += __shfl_xor(s1, off);
    }
    if (lane == 0) {
        float4 nd;
        nd.x = s0; nd.y = s1;
        nd.z = s0 * att_src2[0] + s1 * att_src2[1];
        nd.w = s0 * att_dst2[0] + s1 * att_dst2[1];
        nd4[n] = nd;
    }
}

// ---------------------------------------------------------------------------
// D5: layer-2 aggregation, 16 lanes per dst, contiguous u16 bucket; writes
// d_out.
// ---------------------------------------------------------------------------
__global__ __launch_bounds__(256) void k_agg2(const int* __restrict__ cnt,
                                              const unsigned short* __restrict__ csr16,
                                              const float4* __restrict__ nd4,
                                              const float* __restrict__ b2,
                                              float* __restrict__ out)
{
    const int l = threadIdx.x & 15;
    const int n = blockIdx.x * 16 + (threadIdx.x >> 4);
    if (n >= NN) return;
    int m = cnt[n]; if (m > BCAP) m = BCAP;
    const unsigned short* sp = &csr16[(size_t)n << 6];
    const float ad = nd4[n].w;
    float z = 0.f, a0 = 0.f, a1 = 0.f;
    for (int j = l; j < m; j += 16) {
        int s = sp[j];
        float4 f = nd4[s];
        float ex = __expf(leaky(f.z + ad));
        z  += ex;
        a0 += f.x * ex;
        a1 += f.y * ex;
    }
#pragma unroll
    for (int off = 8; off; off >>= 1) {
        z  += __shfl_xor(z, off);
        a0 += __shfl_xor(a0, off);
        a1 += __shfl_xor(a1, off);
    }
    if (l == 0) {
        out[n * 2 + 0] = a0 / z + b2[0];
        out[n * 2 + 1] = a1 / z + b2[1];
    }
}

extern "C" void kernel_launch(void* const* d_in, const int* in_sizes, int n_in,
                              void* d_out, int out_size, void* d_ws, size_t ws_size,
                              hipStream_t stream)
{
    const float* x        = (const float*)d_in[0];
    const int*   ei       = (const int*)d_in[1];
    const float* W1       = (const float*)d_in[2];
    const float* att_src1 = (const float*)d_in[3];
    const float* att_dst1 = (const float*)d_in[4];
    const float* b1       = (const float*)d_in[5];
    const float* W2       = (const float*)d_in[6];
    const float* att_src2 = (const float*)d_in[7];
    const float* att_dst2 = (const float*)d_in[8];
    const float* b2       = (const float*)d_in[9];
    float* out = (float*)d_out;

    // --- workspace layout (all regions 16B aligned) ---
    unsigned short* csr16 = (unsigned short*)d_ws;           // NN*64*2 = 6.4 MB
    unsigned short* h1b   = csr16 + (size_t)NN * 64;         // 25.6 MB
    unsigned short* Wt_bf = h1b + (size_t)NN * FH;           // 64 KB
    unsigned short* pcnt16 = Wt_bf + FH * FIN;               // NN*32*2 = 3.2 MB
    unsigned short* soff16 = pcnt16 + (size_t)NN * R_REP;    // 3.2 MB
    int*    cnt   = (int*)(soff16 + (size_t)NN * R_REP);     // 200 KB
    float*  a_s1  = (float*)(cnt + NN);                      // 800 KB
    float*  a_d1  = a_s1 + (size_t)NN * 4;                   // 800 KB
    float4* nd4   = (float4*)(a_d1 + (size_t)NN * 4);        // 800 KB

    k_count<<<CNT_WGS + PREP_WGS, 1024, 0, stream>>>(ei, W1, Wt_bf, pcnt16);
    k_gx<<<OFF_NB + GEMM_NB, 256, 0, stream>>>(x, Wt_bf, att_src1, att_dst1,
                                               pcnt16, soff16, cnt, csr16,
                                               h1b, a_s1, a_d1);
    k_scat2<<<CNT_WGS, 1024, 0, stream>>>(ei, soff16, csr16);
    k_agg1<<<(NN + 3) / 4, 256, 0, stream>>>(cnt, csr16, a_s1, a_d1, h1b,
                                             b1, W2, att_src2, att_dst2, nd4);
    k_agg2<<<(NN + 15) / 16, 256, 0, stream>>>(cnt, csr16, nd4, b2, out);
}